// Round 8
// baseline (46.265 us; speedup 1.0000x reference)
//
#include <hip/hip_runtime.h>
#include <hip/hip_bf16.h>

#define NB 16
#define NN 50
#define HW 256

typedef float f32x4 __attribute__((ext_vector_type(4)));  // native vector: valid for nontemporal builtin

// round(linspace(0,256,256))[i] == i + (i>=128); no round-half ties within f32 error.
// Grid value set is {0..127} U {129..256}  (128 is missing).
__device__ __forceinline__ float gridc(int i) { return (float)(i + (i >= 128 ? 1 : 0)); }

// Nearest grid value to continuous coordinate c (c in [5,230] for this problem).
__device__ __forceinline__ float nearest_grid(float c) {
  float r = rintf(c);
  if (r == 128.0f) r = (c < 128.0f) ? 127.0f : 129.0f;  // 128 not in grid; tie -> equal dist
  return r;
}

// R3 structure (best measured: 33.05us) + non-temporal (no-allocate) stores.
// One block = one (b, dest-channel k, 64-row tile); 3200 blocks x 256 threads.
__global__ void k_fused(const float* __restrict__ boxes, const float* __restrict__ labels,
                        float* __restrict__ out) {
  int blk = blockIdx.x;
  int tile = blk & 3;        // 0..3 -> rows tile*64 .. tile*64+63
  int bk = blk >> 2;         // b*NN + k (dest channel)
  int b = bk / NN;
  int k = bk - b * NN;
  int n = (k < 25) ? 2 * k : 2 * (k - 25) + 1;  // channel-shuffle source

  const float4* boxes4 = reinterpret_cast<const float4*>(boxes);
  int t = threadIdx.x;

  // ---- Phase 1 (wave 0): per-batch normalization constants, analytic min/max ----
  // Separable gaussian, all factors > 0: mask extreme = f1 * (1-D ex extreme) * (1-D ey extreme).
  // Max at nearest grid point to center; min at farthest grid endpoint (0 or 256).
  __shared__ float sS, sMns;
  float mn = INFINITY, mx = -INFINITY;
  if (t < NN) {
    float4 bx = boxes4[b * NN + t];
    float xc = bx.x + floorf(bx.z * 0.5f);
    float yc = bx.y + floorf(bx.w * 0.5f);
    float gnx = nearest_grid(xc), gfx = (xc > 128.0f) ? 0.0f : 256.0f;
    float gny = nearest_grid(yc), gfy = (yc > 128.0f) ? 0.0f : 256.0f;
    float dnx = gnx - xc, dfx = gfx - xc, dny = gny - yc, dfy = gfy - yc;
    float exmx = expf(-0.5f * (dnx * dnx) / (0.25f * bx.z));
    float exmn = expf(-0.5f * (dfx * dfx) / (0.25f * bx.z));
    float eymx = expf(-0.5f * (dny * dny) / (0.25f * bx.w));
    float eymn = expf(-0.5f * (dfy * dfy) / (0.25f * bx.w));
    float det = 0.0625f * bx.z * bx.w;
    float f1 = 0.15915494309189535f / sqrtf(det);  // (2*pi)^-1 * det^-0.5
    mn = f1 * exmn * eymn;
    mx = f1 * exmx * eymx;
  }
  if (t < 64) {  // wave 0 reduces channels 0..49 (lanes 50..63 hold identities)
#pragma unroll
    for (int o = 32; o > 0; o >>= 1) {
      mn = fminf(mn, __shfl_xor(mn, o));
      mx = fmaxf(mx, __shfl_xor(mx, o));
    }
    if (t == 0) {
      float s = 50.0f / (mx - mn);  // SCALE_FACTOR / (mx - mn)
      sS = s;
      sMns = mn * s;
    }
  }

  // ---- labels: the 16 (k==0, tile==0) blocks write their batch's 50 permuted labels ----
  if (k == 0 && tile == 0 && t < NN) {
    int src = (t < 25) ? 2 * t : 2 * (t - 25) + 1;
    out[(size_t)NB * NN * HW * HW + b * NN + t] = labels[b * NN + src];
  }

  // ---- Phase 2: separable exp tables for THIS channel ----
  float4 box = boxes4[b * NN + n];
  float xc = box.x + floorf(box.z * 0.5f);
  float yc = box.y + floorf(box.w * 0.5f);
  float det = 0.0625f * box.z * box.w;
  float f1 = 0.15915494309189535f / sqrtf(det);

  __shared__ float eyL[HW];
  __shared__ float exL[64];
  {
    float g = gridc(t);
    float dy = g - yc;
    eyL[t] = expf(-0.5f * (dy * dy) / (0.25f * box.w));
  }
  int row0 = tile * 64;
  if (t < 64) {
    float g = gridc(row0 + t);
    float dx = g - xc;
    exL[t] = expf(-0.5f * (dx * dx) / (0.25f * box.z));
  }
  __syncthreads();

  float A = f1 * sS;     // folded factor1 * scale
  float mns = sMns;

  int lane_col = (t & 63) * 4;  // one 64-lane wave spans a 1 KB row, f32x4 each
  int rsub = t >> 6;            // 0..3: 4 waves write 4 consecutive rows -> 4 KB bursts
  float eyr[4];
#pragma unroll
  for (int c = 0; c < 4; ++c) eyr[c] = A * eyL[lane_col + c];  // A folded, reused 16x

  float* base = out + (size_t)bk * (HW * HW) + (size_t)row0 * HW;
#pragma unroll
  for (int it = 0; it < 16; ++it) {
    int r = rsub + it * 4;      // 0..63 within tile
    float coef = exL[r];
    f32x4 v;
    v.x = fmaf(coef, eyr[0], -mns);   // mask*s - mn*s
    v.y = fmaf(coef, eyr[1], -mns);
    v.z = fmaf(coef, eyr[2], -mns);
    v.w = fmaf(coef, eyr[3], -mns);
    __builtin_nontemporal_store(v, reinterpret_cast<f32x4*>(base + r * HW + lane_col));
  }
}

extern "C" void kernel_launch(void* const* d_in, const int* in_sizes, int n_in,
                              void* d_out, int out_size, void* d_ws, size_t ws_size,
                              hipStream_t stream) {
  const float* boxes = (const float*)d_in[0];
  const float* labels = (const float*)d_in[1];
  float* out = (float*)d_out;
  k_fused<<<NB * NN * 4, 256, 0, stream>>>(boxes, labels, out);
}

// Round 9
// 33.145 us; speedup vs baseline: 1.3958x; 1.3958x over previous
//
#include <hip/hip_runtime.h>
#include <hip/hip_bf16.h>

#define NB 16
#define NN 50
#define HW 256

// round(linspace(0,256,256))[i] == i + (i>=128); no round-half ties within f32 error.
// Grid value set is {0..127} U {129..256}  (128 is missing).
__device__ __forceinline__ float gridc(int i) { return (float)(i + (i >= 128 ? 1 : 0)); }

// Nearest grid value to continuous coordinate c (c in [5,230] for this problem).
__device__ __forceinline__ float nearest_grid(float c) {
  float r = rintf(c);
  if (r == 128.0f) r = (c < 128.0f) ? 127.0f : 129.0f;  // 128 not in grid; tie -> equal dist
  return r;
}

// Best-measured structure (R3: 33.05us = ~93% of the fill-kernel store ceiling).
// One block = one (b, dest-channel k, 64-row tile); 3200 blocks x 256 threads.
// NOTE: nontemporal stores were tried (R8) and regressed 40% -- L2 write-aggregation
// is load-bearing for the store stream on gfx950; keep plain dwordx4 stores.
__global__ void k_fused(const float* __restrict__ boxes, const float* __restrict__ labels,
                        float* __restrict__ out) {
  int blk = blockIdx.x;
  int tile = blk & 3;        // 0..3 -> rows tile*64 .. tile*64+63
  int bk = blk >> 2;         // b*NN + k (dest channel)
  int b = bk / NN;
  int k = bk - b * NN;
  int n = (k < 25) ? 2 * k : 2 * (k - 25) + 1;  // channel-shuffle source

  const float4* boxes4 = reinterpret_cast<const float4*>(boxes);
  int t = threadIdx.x;

  // ---- Phase 1 (wave 0): per-batch normalization constants, analytic min/max ----
  // Separable gaussian, all factors > 0: mask extreme = f1 * (1-D ex extreme) * (1-D ey extreme).
  // Max at nearest grid point to center; min at farthest grid endpoint (0 or 256).
  __shared__ float sS, sMns;
  float mn = INFINITY, mx = -INFINITY;
  if (t < NN) {
    float4 bx = boxes4[b * NN + t];
    float xc = bx.x + floorf(bx.z * 0.5f);
    float yc = bx.y + floorf(bx.w * 0.5f);
    float gnx = nearest_grid(xc), gfx = (xc > 128.0f) ? 0.0f : 256.0f;
    float gny = nearest_grid(yc), gfy = (yc > 128.0f) ? 0.0f : 256.0f;
    float dnx = gnx - xc, dfx = gfx - xc, dny = gny - yc, dfy = gfy - yc;
    float exmx = expf(-0.5f * (dnx * dnx) / (0.25f * bx.z));
    float exmn = expf(-0.5f * (dfx * dfx) / (0.25f * bx.z));
    float eymx = expf(-0.5f * (dny * dny) / (0.25f * bx.w));
    float eymn = expf(-0.5f * (dfy * dfy) / (0.25f * bx.w));
    float det = 0.0625f * bx.z * bx.w;
    float f1 = 0.15915494309189535f / sqrtf(det);  // (2*pi)^-1 * det^-0.5
    mn = f1 * exmn * eymn;
    mx = f1 * exmx * eymx;
  }
  if (t < 64) {  // wave 0 reduces channels 0..49 (lanes 50..63 hold identities)
#pragma unroll
    for (int o = 32; o > 0; o >>= 1) {
      mn = fminf(mn, __shfl_xor(mn, o));
      mx = fmaxf(mx, __shfl_xor(mx, o));
    }
    if (t == 0) {
      float s = 50.0f / (mx - mn);  // SCALE_FACTOR / (mx - mn)
      sS = s;
      sMns = mn * s;
    }
  }

  // ---- labels: the 16 (k==0, tile==0) blocks write their batch's 50 permuted labels ----
  if (k == 0 && tile == 0 && t < NN) {
    int src = (t < 25) ? 2 * t : 2 * (t - 25) + 1;
    out[(size_t)NB * NN * HW * HW + b * NN + t] = labels[b * NN + src];
  }

  // ---- Phase 2: separable exp tables for THIS channel ----
  float4 box = boxes4[b * NN + n];
  float xc = box.x + floorf(box.z * 0.5f);
  float yc = box.y + floorf(box.w * 0.5f);
  float det = 0.0625f * box.z * box.w;
  float f1 = 0.15915494309189535f / sqrtf(det);

  __shared__ float eyL[HW];
  __shared__ float exL[64];
  {
    float g = gridc(t);
    float dy = g - yc;
    eyL[t] = expf(-0.5f * (dy * dy) / (0.25f * box.w));
  }
  int row0 = tile * 64;
  if (t < 64) {
    float g = gridc(row0 + t);
    float dx = g - xc;
    exL[t] = expf(-0.5f * (dx * dx) / (0.25f * box.z));
  }
  __syncthreads();

  float A = f1 * sS;     // folded factor1 * scale
  float mns = sMns;

  int lane_col = (t & 63) * 4;  // one 64-lane wave spans a 1 KB row, float4 each
  int rsub = t >> 6;            // 0..3: 4 waves write 4 consecutive rows -> 4 KB bursts
  float eyr[4];
#pragma unroll
  for (int c = 0; c < 4; ++c) eyr[c] = A * eyL[lane_col + c];  // A folded, reused 16x

  float* base = out + (size_t)bk * (HW * HW) + (size_t)row0 * HW;
#pragma unroll
  for (int it = 0; it < 16; ++it) {
    int r = rsub + it * 4;      // 0..63 within tile
    float coef = exL[r];
    float4 v;
    v.x = fmaf(coef, eyr[0], -mns);   // mask*s - mn*s
    v.y = fmaf(coef, eyr[1], -mns);
    v.z = fmaf(coef, eyr[2], -mns);
    v.w = fmaf(coef, eyr[3], -mns);
    *reinterpret_cast<float4*>(base + r * HW + lane_col) = v;
  }
}

extern "C" void kernel_launch(void* const* d_in, const int* in_sizes, int n_in,
                              void* d_out, int out_size, void* d_ws, size_t ws_size,
                              hipStream_t stream) {
  const float* boxes = (const float*)d_in[0];
  const float* labels = (const float*)d_in[1];
  float* out = (float*)d_out;
  k_fused<<<NB * NN * 4, 256, 0, stream>>>(boxes, labels, out);
}